// Round 1
// baseline (119.509 us; speedup 1.0000x reference)
//
#include <hip/hip_runtime.h>

#define NB 8
#define TS 16
#define PR 20  // product region (tile + 2 halo each side)
#define GR 22  // g1 region (tile + 3 halo each side)

__global__ void gray_kernel(const float* __restrict__ img1, const float* __restrict__ img2,
                            float* __restrict__ g1, float* __restrict__ g2, int HW) {
    int i = blockIdx.x * blockDim.x + threadIdx.x;
    if (i >= NB * HW) return;
    int b = i / HW, p = i % HW;
    const float* a = img1 + (size_t)b * 3 * HW + p;
    const float* c = img2 + (size_t)b * 3 * HW + p;
    g1[i] = (a[0] + a[HW] + a[2 * HW]) * (1.0f / 3.0f);
    g2[i] = (c[0] + c[HW] + c[2 * HW]) * (1.0f / 3.0f);
}

__global__ void down_kernel(const float* __restrict__ in, float* __restrict__ out,
                            int Hi, int Wi) {
    int Ho = Hi >> 1, Wo = Wi >> 1;
    int i = blockIdx.x * blockDim.x + threadIdx.x;
    int total = NB * Ho * Wo;
    if (i >= total) return;
    int b = i / (Ho * Wo);
    int r = i % (Ho * Wo);
    int y = r / Wo, x = r % Wo;
    const float* p = in + ((size_t)b * Hi + 2 * y) * Wi + 2 * x;
    out[i] = (p[0] + p[1] + p[Wi] + p[Wi + 1]) * 0.25f;
}

// align_corners=True bilinear 2x upsample of flow (B,2,Hs,Ws)->(B,2,2Hs,2Ws), then *2.0
__global__ void upsample_flow(const float* __restrict__ fin, float* __restrict__ fout,
                              int Hs, int Ws) {
    int Ht = Hs * 2, Wt = Ws * 2;
    int i = blockIdx.x * blockDim.x + threadIdx.x;
    int total = NB * 2 * Ht * Wt;
    if (i >= total) return;
    int x = i % Wt;
    int t = i / Wt;
    int y = t % Ht;
    t /= Ht;  // t = b*2 + c
    float sy = (float)y * (float)(Hs - 1) / (float)(Ht - 1);
    float sx = (float)x * (float)(Ws - 1) / (float)(Wt - 1);
    int y0 = (int)sy; if (y0 > Hs - 2) y0 = Hs - 2;
    int x0 = (int)sx; if (x0 > Ws - 2) x0 = Ws - 2;
    float wy = sy - (float)y0, wx = sx - (float)x0;
    const float* p = fin + ((size_t)t * Hs + y0) * Ws + x0;
    float top = p[0] * (1.0f - wy) + p[Ws] * wy;
    float bot = p[1] * (1.0f - wy) + p[Ws + 1] * wy;
    fout[i] = 2.0f * (top * (1.0f - wx) + bot * wx);
}

// Fused per-level LK: warp + Sobel + It + 5x5 box + 2x2 solve + flow update.
// One 16x16 output tile per block; products computed for the 20x20 halo region in LDS.
__global__ __launch_bounds__(256) void lk_kernel(
    const float* __restrict__ g1, const float* __restrict__ g2,
    const float* __restrict__ fin, float* __restrict__ fout, int H, int W) {
    __shared__ float sG[GR][GR];
    __shared__ float sU[PR][PR], sV[PR][PR];
    __shared__ float sP[5][PR][PR];

    int b = blockIdx.z;
    int ty0 = blockIdx.y * TS, tx0 = blockIdx.x * TS;
    int tid = threadIdx.y * TS + threadIdx.x;
    const float* G1 = g1 + (size_t)b * H * W;
    const float* G2 = g2 + (size_t)b * H * W;
    const float* FU = fin + (size_t)b * 2 * H * W;
    const float* FV = FU + H * W;

    for (int i = tid; i < GR * GR; i += 256) {
        int r = i / GR, c = i % GR;
        int gy = ty0 - 3 + r, gx = tx0 - 3 + c;
        float v = 0.0f;
        if (gy >= 0 && gy < H && gx >= 0 && gx < W) v = G1[gy * W + gx];
        sG[r][c] = v;
    }
    for (int i = tid; i < PR * PR; i += 256) {
        int r = i / PR, c = i % PR;
        int gy = ty0 - 2 + r, gx = tx0 - 2 + c;
        float u = 0.0f, v = 0.0f;
        if (gy >= 0 && gy < H && gx >= 0 && gx < W) {
            u = FU[gy * W + gx];
            v = FV[gy * W + gx];
        }
        sU[r][c] = u;
        sV[r][c] = v;
    }
    __syncthreads();

    for (int i = tid; i < PR * PR; i += 256) {
        int r = i / PR, c = i % PR;
        int gy = ty0 - 2 + r, gx = tx0 - 2 + c;
        float pxx = 0.f, pyy = 0.f, pxy = 0.f, pxt = 0.f, pyt = 0.f;
        if (gy >= 0 && gy < H && gx >= 0 && gx < W) {
            // Sobel/8 (cross-correlation, zero-padded): center at sG[r+1][c+1]
            float Ix = (-sG[r][c] + sG[r][c + 2]
                        - 2.0f * sG[r + 1][c] + 2.0f * sG[r + 1][c + 2]
                        - sG[r + 2][c] + sG[r + 2][c + 2]) * 0.125f;
            float Iy = (-sG[r][c] - 2.0f * sG[r][c + 1] - sG[r][c + 2]
                        + sG[r + 2][c] + 2.0f * sG[r + 2][c + 1] + sG[r + 2][c + 2]) * 0.125f;
            // bilinear warp of G2 at (gx+u, gy+v), zeros padding, per-corner validity
            float su = sU[r][c], sv = sV[r][c];
            float xx = (float)gx + su, yy = (float)gy + sv;
            float x0f = floorf(xx), y0f = floorf(yy);
            float wx = xx - x0f, wy = yy - y0f;
            bool vx0 = (x0f >= 0.0f) && (x0f <= (float)(W - 1));
            bool vx1 = (x0f + 1.0f >= 0.0f) && (x0f + 1.0f <= (float)(W - 1));
            bool vy0 = (y0f >= 0.0f) && (y0f <= (float)(H - 1));
            bool vy1 = (y0f + 1.0f >= 0.0f) && (y0f + 1.0f <= (float)(H - 1));
            int xi = (int)x0f, yi = (int)y0f;
            int xc0 = min(max(xi, 0), W - 1), xc1 = min(max(xi + 1, 0), W - 1);
            int yc0 = min(max(yi, 0), H - 1), yc1 = min(max(yi + 1, 0), H - 1);
            float v00 = 0.f, v01 = 0.f, v10 = 0.f, v11 = 0.f;
            if (vy0) {
                const float* row = G2 + yc0 * W;
                if (vx0) v00 = row[xc0];
                if (vx1) v01 = row[xc1];
            }
            if (vy1) {
                const float* row = G2 + yc1 * W;
                if (vx0) v10 = row[xc0];
                if (vx1) v11 = row[xc1];
            }
            float I2w = v00 * ((1.0f - wx) * (1.0f - wy)) + v01 * (wx * (1.0f - wy))
                      + v10 * ((1.0f - wx) * wy) + v11 * (wx * wy);
            float It = I2w - sG[r + 1][c + 1];
            pxx = Ix * Ix; pyy = Iy * Iy; pxy = Ix * Iy;
            pxt = Ix * It; pyt = Iy * It;
        }
        sP[0][r][c] = pxx;
        sP[1][r][c] = pyy;
        sP[2][r][c] = pxy;
        sP[3][r][c] = pxt;
        sP[4][r][c] = pyt;
    }
    __syncthreads();

    int ly = threadIdx.y, lx = threadIdx.x;
    float Sxx = 0.f, Syy = 0.f, Sxy = 0.f, Sxt = 0.f, Syt = 0.f;
#pragma unroll
    for (int r = 0; r < 5; ++r) {
#pragma unroll
        for (int c = 0; c < 5; ++c) {
            Sxx += sP[0][ly + r][lx + c];
            Syy += sP[1][ly + r][lx + c];
            Sxy += sP[2][ly + r][lx + c];
            Sxt += sP[3][ly + r][lx + c];
            Syt += sP[4][ly + r][lx + c];
        }
    }
    float inv = 1.0f / (Sxx * Syy - Sxy * Sxy + 1e-6f);
    float du = (-Syy * Sxt + Sxy * Syt) * inv;
    float dv = (Sxy * Sxt - Sxx * Syt) * inv;
    int gy = ty0 + ly, gx = tx0 + lx;
    float* FOU = fout + (size_t)b * 2 * H * W;
    FOU[gy * W + gx] = sU[ly + 2][lx + 2] + du;
    FOU[H * W + gy * W + gx] = sV[ly + 2][lx + 2] + dv;
}

extern "C" void kernel_launch(void* const* d_in, const int* in_sizes, int n_in,
                              void* d_out, int out_size, void* d_ws, size_t ws_size,
                              hipStream_t stream) {
    const float* img1 = (const float*)d_in[0];
    const float* img2 = (const float*)d_in[1];
    float* out = (float*)d_out;
    float* ws = (float*)d_ws;

    const int Hl[4] = {512, 256, 128, 64};
    size_t goff[4];
    size_t tot = 0;
    for (int l = 0; l < 4; ++l) {
        goff[l] = tot;
        tot += (size_t)NB * Hl[l] * Hl[l];
    }
    float* g1 = ws;
    float* g2 = ws + tot;
    float* fA = g2 + tot;
    float* fB = fA + (size_t)NB * 2 * 512 * 512;

    // 1. gray at full res
    {
        int n = NB * 512 * 512;
        gray_kernel<<<(n + 255) / 256, 256, 0, stream>>>(img1, img2, g1, g2, 512 * 512);
    }
    // 2. pyramids
    for (int l = 1; l < 4; ++l) {
        int Hi = Hl[l - 1];
        int n = NB * (Hi / 2) * (Hi / 2);
        down_kernel<<<(n + 255) / 256, 256, 0, stream>>>(g1 + goff[l - 1], g1 + goff[l], Hi, Hi);
        down_kernel<<<(n + 255) / 256, 256, 0, stream>>>(g2 + goff[l - 1], g2 + goff[l], Hi, Hi);
    }
    // 3. zero flow at coarsest
    hipMemsetAsync(fA, 0, (size_t)NB * 2 * 64 * 64 * sizeof(float), stream);
    // 4. level 3 (64x64)
    {
        dim3 gr(64 / TS, 64 / TS, NB), bl(TS, TS);
        lk_kernel<<<gr, bl, 0, stream>>>(g1 + goff[3], g2 + goff[3], fA, fB, 64, 64);
    }
    // 5. levels 2..0
    for (int l = 2; l >= 0; --l) {
        int Hs = Hl[l + 1], Ht = Hl[l];
        int n = NB * 2 * Ht * Ht;
        upsample_flow<<<(n + 255) / 256, 256, 0, stream>>>(fB, fA, Hs, Hs);
        dim3 gr(Ht / TS, Ht / TS, NB), bl(TS, TS);
        float* dst = (l == 0) ? out : fB;
        lk_kernel<<<gr, bl, 0, stream>>>(g1 + goff[l], g2 + goff[l], fA, dst, Ht, Ht);
    }
}

// Round 2
// 77.503 us; speedup vs baseline: 1.5420x; 1.5420x over previous
//
#include <hip/hip_runtime.h>

#define NB 8
#define TS 16
#define PR 20   // product region (tile + 2 halo each side)
#define GR 22   // g1 region (tile + 3 halo each side)
#define SW 24   // padded LDS row stride (24 % 32 -> uniform 2-way = free)

// Fused: channel-mean gray of both 512x512 images + 2x2 avg-pool to level 1.
// One thread per 2x2 quad; float2 loads/stores.
__global__ void gray_pool_kernel(const float* __restrict__ img1, const float* __restrict__ img2,
                                 float* __restrict__ g0a, float* __restrict__ g0b,
                                 float* __restrict__ g1a, float* __restrict__ g1b) {
    const int W = 512, HW = 512 * 512, Wq = 256, HWq = 256 * 256;
    int i = blockIdx.x * blockDim.x + threadIdx.x;
    if (i >= NB * HWq) return;
    int qx = i % Wq;
    int qy = (i / Wq) % Wq;
    int b = i / HWq;
    size_t base = (size_t)b * 3 * HW + (size_t)(2 * qy) * W + 2 * qx;
    const float third = 1.0f / 3.0f;

    float2 a0c0 = *(const float2*)(img1 + base);
    float2 a1c0 = *(const float2*)(img1 + base + W);
    float2 a0c1 = *(const float2*)(img1 + base + HW);
    float2 a1c1 = *(const float2*)(img1 + base + HW + W);
    float2 a0c2 = *(const float2*)(img1 + base + 2 * HW);
    float2 a1c2 = *(const float2*)(img1 + base + 2 * HW + W);
    float p00 = (a0c0.x + a0c1.x + a0c2.x) * third;
    float p01 = (a0c0.y + a0c1.y + a0c2.y) * third;
    float p10 = (a1c0.x + a1c1.x + a1c2.x) * third;
    float p11 = (a1c0.y + a1c1.y + a1c2.y) * third;
    size_t gbase = (size_t)b * HW + (size_t)(2 * qy) * W + 2 * qx;
    *(float2*)(g0a + gbase) = make_float2(p00, p01);
    *(float2*)(g0a + gbase + W) = make_float2(p10, p11);
    g1a[(size_t)b * HWq + qy * Wq + qx] = (p00 + p01 + p10 + p11) * 0.25f;

    float2 b0c0 = *(const float2*)(img2 + base);
    float2 b1c0 = *(const float2*)(img2 + base + W);
    float2 b0c1 = *(const float2*)(img2 + base + HW);
    float2 b1c1 = *(const float2*)(img2 + base + HW + W);
    float2 b0c2 = *(const float2*)(img2 + base + 2 * HW);
    float2 b1c2 = *(const float2*)(img2 + base + 2 * HW + W);
    float q00 = (b0c0.x + b0c1.x + b0c2.x) * third;
    float q01 = (b0c0.y + b0c1.y + b0c2.y) * third;
    float q10 = (b1c0.x + b1c1.x + b1c2.x) * third;
    float q11 = (b1c0.y + b1c1.y + b1c2.y) * third;
    *(float2*)(g0b + gbase) = make_float2(q00, q01);
    *(float2*)(g0b + gbase + W) = make_float2(q10, q11);
    g1b[(size_t)b * HWq + qy * Wq + qx] = (q00 + q01 + q10 + q11) * 0.25f;
}

__global__ void down_kernel(const float* __restrict__ in, float* __restrict__ out,
                            int Hi, int Wi) {
    int Ho = Hi >> 1, Wo = Wi >> 1;
    int i = blockIdx.x * blockDim.x + threadIdx.x;
    int total = NB * Ho * Wo;
    if (i >= total) return;
    int b = i / (Ho * Wo);
    int r = i % (Ho * Wo);
    int y = r / Wo, x = r % Wo;
    const float* p = in + ((size_t)b * Hi + 2 * y) * Wi + 2 * x;
    out[i] = (p[0] + p[1] + p[Wi] + p[Wi + 1]) * 0.25f;
}

// Fused per-level LK: inline flow upsample (MODE=1) or zero flow (MODE=0),
// warp + Sobel + It + products, separable 5x5 box, 2x2 solve, flow update.
// 1-D swizzled grid: b = blockIdx.x % NB pins each batch to one XCD.
template <int MODE>
__global__ __launch_bounds__(256) void lk_kernel(
    const float* __restrict__ g1, const float* __restrict__ g2,
    const float* __restrict__ fin, float* __restrict__ fout, int H, int W) {
    __shared__ float sG[GR][SW];
    __shared__ float sU[PR][SW], sV[PR][SW];
    __shared__ float sP[5][PR][SW];
    __shared__ float sH[5][PR][16];

    int nbx = W / TS;
    int b = blockIdx.x % NB;
    int t = blockIdx.x / NB;
    int ty0 = (t / nbx) * TS, tx0 = (t % nbx) * TS;
    int tid = threadIdx.x;
    int lx = tid % TS, ly = tid / TS;

    const float* G1 = g1 + (size_t)b * H * W;
    const float* G2 = g2 + (size_t)b * H * W;

    // phase 0: stage G1 tile with halo 3 (zero-padded)
    for (int i = tid; i < GR * GR; i += 256) {
        int r = i / GR, c = i % GR;
        int gy = ty0 - 3 + r, gx = tx0 - 3 + c;
        float v = 0.0f;
        if (gy >= 0 && gy < H && gx >= 0 && gx < W) v = G1[gy * W + gx];
        sG[r][c] = v;
    }
    // phase 1: flow for the 20x20 region (inline align-corners 2x upsample *2)
    if (MODE == 1) {
        int Hs = H >> 1, Ws = W >> 1;
        float scale = (float)(Hs - 1) / (float)(H - 1);
        const float* FU = fin + (size_t)b * 2 * Hs * Ws;
        const float* FV = FU + Hs * Ws;
        for (int i = tid; i < PR * PR; i += 256) {
            int r = i / PR, c = i % PR;
            int gy = ty0 - 2 + r, gx = tx0 - 2 + c;
            float u = 0.0f, v = 0.0f;
            if (gy >= 0 && gy < H && gx >= 0 && gx < W) {
                float sy = (float)gy * scale;
                float sx = (float)gx * scale;
                int y0 = (int)sy; if (y0 > Hs - 2) y0 = Hs - 2;
                int x0 = (int)sx; if (x0 > Ws - 2) x0 = Ws - 2;
                float wy = sy - (float)y0, wx = sx - (float)x0;
                const float* pu = FU + (size_t)y0 * Ws + x0;
                const float* pv = FV + (size_t)y0 * Ws + x0;
                float ut = pu[0] * (1.0f - wy) + pu[Ws] * wy;
                float ub = pu[1] * (1.0f - wy) + pu[Ws + 1] * wy;
                float vt = pv[0] * (1.0f - wy) + pv[Ws] * wy;
                float vb = pv[1] * (1.0f - wy) + pv[Ws + 1] * wy;
                u = 2.0f * (ut * (1.0f - wx) + ub * wx);
                v = 2.0f * (vt * (1.0f - wx) + vb * wx);
            }
            sU[r][c] = u;
            sV[r][c] = v;
        }
    } else {
        for (int i = tid; i < PR * PR; i += 256) {
            int r = i / PR, c = i % PR;
            sU[r][c] = 0.0f;
            sV[r][c] = 0.0f;
        }
    }
    __syncthreads();

    // phase 2: Sobel + warp + It + 5 products for the 20x20 region
    for (int i = tid; i < PR * PR; i += 256) {
        int r = i / PR, c = i % PR;
        int gy = ty0 - 2 + r, gx = tx0 - 2 + c;
        float pxx = 0.f, pyy = 0.f, pxy = 0.f, pxt = 0.f, pyt = 0.f;
        if (gy >= 0 && gy < H && gx >= 0 && gx < W) {
            float Ix = (-sG[r][c] + sG[r][c + 2]
                        - 2.0f * sG[r + 1][c] + 2.0f * sG[r + 1][c + 2]
                        - sG[r + 2][c] + sG[r + 2][c + 2]) * 0.125f;
            float Iy = (-sG[r][c] - 2.0f * sG[r][c + 1] - sG[r][c + 2]
                        + sG[r + 2][c] + 2.0f * sG[r + 2][c + 1] + sG[r + 2][c + 2]) * 0.125f;
            float su = sU[r][c], sv = sV[r][c];
            float xx = (float)gx + su, yy = (float)gy + sv;
            float x0f = floorf(xx), y0f = floorf(yy);
            float wx = xx - x0f, wy = yy - y0f;
            bool vx0 = (x0f >= 0.0f) && (x0f <= (float)(W - 1));
            bool vx1 = (x0f + 1.0f >= 0.0f) && (x0f + 1.0f <= (float)(W - 1));
            bool vy0 = (y0f >= 0.0f) && (y0f <= (float)(H - 1));
            bool vy1 = (y0f + 1.0f >= 0.0f) && (y0f + 1.0f <= (float)(H - 1));
            int xi = (int)x0f, yi = (int)y0f;
            int xc0 = min(max(xi, 0), W - 1), xc1 = min(max(xi + 1, 0), W - 1);
            int yc0 = min(max(yi, 0), H - 1), yc1 = min(max(yi + 1, 0), H - 1);
            float v00 = 0.f, v01 = 0.f, v10 = 0.f, v11 = 0.f;
            if (vy0) {
                const float* row = G2 + yc0 * W;
                if (vx0) v00 = row[xc0];
                if (vx1) v01 = row[xc1];
            }
            if (vy1) {
                const float* row = G2 + yc1 * W;
                if (vx0) v10 = row[xc0];
                if (vx1) v11 = row[xc1];
            }
            float I2w = v00 * ((1.0f - wx) * (1.0f - wy)) + v01 * (wx * (1.0f - wy))
                      + v10 * ((1.0f - wx) * wy) + v11 * (wx * wy);
            float It = I2w - sG[r + 1][c + 1];
            pxx = Ix * Ix; pyy = Iy * Iy; pxy = Ix * Iy;
            pxt = Ix * It; pyt = Iy * It;
        }
        sP[0][r][c] = pxx;
        sP[1][r][c] = pyy;
        sP[2][r][c] = pxy;
        sP[3][r][c] = pxt;
        sP[4][r][c] = pyt;
    }
    __syncthreads();

    // phase 3: horizontal 5-sums -> sH[ch][r][x], r in [0,20), x in [0,16)
    for (int i = tid; i < 5 * PR * 16; i += 256) {
        int ch = i / (PR * 16);
        int rem = i % (PR * 16);
        int r = rem / 16, x = rem % 16;
        const float* row = &sP[ch][r][x];
        sH[ch][r][x] = row[0] + row[1] + row[2] + row[3] + row[4];
    }
    __syncthreads();

    // phase 4: vertical 5-sums + 2x2 solve + flow update
    float Sxx = 0.f, Syy = 0.f, Sxy = 0.f, Sxt = 0.f, Syt = 0.f;
#pragma unroll
    for (int dy = 0; dy < 5; ++dy) {
        Sxx += sH[0][ly + dy][lx];
        Syy += sH[1][ly + dy][lx];
        Sxy += sH[2][ly + dy][lx];
        Sxt += sH[3][ly + dy][lx];
        Syt += sH[4][ly + dy][lx];
    }
    float inv = 1.0f / (Sxx * Syy - Sxy * Sxy + 1e-6f);
    float du = (-Syy * Sxt + Sxy * Syt) * inv;
    float dv = (Sxy * Sxt - Sxx * Syt) * inv;
    int gy = ty0 + ly, gx = tx0 + lx;
    float* FOU = fout + (size_t)b * 2 * H * W;
    FOU[gy * W + gx] = sU[ly + 2][lx + 2] + du;
    FOU[H * W + gy * W + gx] = sV[ly + 2][lx + 2] + dv;
}

extern "C" void kernel_launch(void* const* d_in, const int* in_sizes, int n_in,
                              void* d_out, int out_size, void* d_ws, size_t ws_size,
                              hipStream_t stream) {
    const float* img1 = (const float*)d_in[0];
    const float* img2 = (const float*)d_in[1];
    float* out = (float*)d_out;
    float* ws = (float*)d_ws;

    const int Hl[4] = {512, 256, 128, 64};
    size_t goff[4];
    size_t tot = 0;
    for (int l = 0; l < 4; ++l) {
        goff[l] = tot;
        tot += (size_t)NB * Hl[l] * Hl[l];
    }
    float* p1 = ws;            // gray pyramid img1
    float* p2 = ws + tot;      // gray pyramid img2
    float* f64 = p2 + tot;
    float* f128 = f64 + (size_t)NB * 2 * 64 * 64;
    float* f256 = f128 + (size_t)NB * 2 * 128 * 128;

    // gray @512 + pool to @256 (both images), fused
    {
        int n = NB * 256 * 256;
        gray_pool_kernel<<<(n + 255) / 256, 256, 0, stream>>>(
            img1, img2, p1 + goff[0], p2 + goff[0], p1 + goff[1], p2 + goff[1]);
    }
    // pyramids: 256->128->64
    for (int l = 2; l < 4; ++l) {
        int Hi = Hl[l - 1];
        int n = NB * (Hi / 2) * (Hi / 2);
        down_kernel<<<(n + 255) / 256, 256, 0, stream>>>(p1 + goff[l - 1], p1 + goff[l], Hi, Hi);
        down_kernel<<<(n + 255) / 256, 256, 0, stream>>>(p2 + goff[l - 1], p2 + goff[l], Hi, Hi);
    }
    // coarse-to-fine LK
    {
        int nb = NB * (64 / TS) * (64 / TS);
        lk_kernel<0><<<nb, 256, 0, stream>>>(p1 + goff[3], p2 + goff[3], nullptr, f64, 64, 64);
    }
    {
        int nb = NB * (128 / TS) * (128 / TS);
        lk_kernel<1><<<nb, 256, 0, stream>>>(p1 + goff[2], p2 + goff[2], f64, f128, 128, 128);
    }
    {
        int nb = NB * (256 / TS) * (256 / TS);
        lk_kernel<1><<<nb, 256, 0, stream>>>(p1 + goff[1], p2 + goff[1], f128, f256, 256, 256);
    }
    {
        int nb = NB * (512 / TS) * (512 / TS);
        lk_kernel<1><<<nb, 256, 0, stream>>>(p1 + goff[0], p2 + goff[0], f256, out, 512, 512);
    }
}

// Round 4
// 70.855 us; speedup vs baseline: 1.6867x; 1.0938x over previous
//
#include <hip/hip_runtime.h>

#define NB 8
#define TS 16
#define PR 20   // product region (tile + 2 halo each side)
#define GR 22   // g1 region (tile + 3 halo each side)
#define SW 24   // padded LDS row stride (24 % 32 -> uniform 2-way = free)

typedef float f2 __attribute__((ext_vector_type(2)));

// Fused: channel-mean gray of both 512x512 images + 2x2 avg-pool to level 1.
// One thread per 2x2 quad; nontemporal vector loads (stream-once inputs).
__global__ void gray_pool_kernel(const float* __restrict__ img1, const float* __restrict__ img2,
                                 float* __restrict__ g0a, float* __restrict__ g0b,
                                 float* __restrict__ g1a, float* __restrict__ g1b) {
    const int W = 512, HW = 512 * 512, Wq = 256, HWq = 256 * 256;
    int i = blockIdx.x * blockDim.x + threadIdx.x;
    if (i >= NB * HWq) return;
    int qx = i % Wq;
    int qy = (i / Wq) % Wq;
    int b = i / HWq;
    size_t base = (size_t)b * 3 * HW + (size_t)(2 * qy) * W + 2 * qx;
    const float third = 1.0f / 3.0f;

    f2 a0c0 = __builtin_nontemporal_load((const f2*)(img1 + base));
    f2 a1c0 = __builtin_nontemporal_load((const f2*)(img1 + base + W));
    f2 a0c1 = __builtin_nontemporal_load((const f2*)(img1 + base + HW));
    f2 a1c1 = __builtin_nontemporal_load((const f2*)(img1 + base + HW + W));
    f2 a0c2 = __builtin_nontemporal_load((const f2*)(img1 + base + 2 * HW));
    f2 a1c2 = __builtin_nontemporal_load((const f2*)(img1 + base + 2 * HW + W));
    float p00 = (a0c0.x + a0c1.x + a0c2.x) * third;
    float p01 = (a0c0.y + a0c1.y + a0c2.y) * third;
    float p10 = (a1c0.x + a1c1.x + a1c2.x) * third;
    float p11 = (a1c0.y + a1c1.y + a1c2.y) * third;
    size_t gbase = (size_t)b * HW + (size_t)(2 * qy) * W + 2 * qx;
    *(f2*)(g0a + gbase) = (f2){p00, p01};
    *(f2*)(g0a + gbase + W) = (f2){p10, p11};
    g1a[(size_t)b * HWq + qy * Wq + qx] = (p00 + p01 + p10 + p11) * 0.25f;

    f2 b0c0 = __builtin_nontemporal_load((const f2*)(img2 + base));
    f2 b1c0 = __builtin_nontemporal_load((const f2*)(img2 + base + W));
    f2 b0c1 = __builtin_nontemporal_load((const f2*)(img2 + base + HW));
    f2 b1c1 = __builtin_nontemporal_load((const f2*)(img2 + base + HW + W));
    f2 b0c2 = __builtin_nontemporal_load((const f2*)(img2 + base + 2 * HW));
    f2 b1c2 = __builtin_nontemporal_load((const f2*)(img2 + base + 2 * HW + W));
    float q00 = (b0c0.x + b0c1.x + b0c2.x) * third;
    float q01 = (b0c0.y + b0c1.y + b0c2.y) * third;
    float q10 = (b1c0.x + b1c1.x + b1c2.x) * third;
    float q11 = (b1c0.y + b1c1.y + b1c2.y) * third;
    *(f2*)(g0b + gbase) = (f2){q00, q01};
    *(f2*)(g0b + gbase + W) = (f2){q10, q11};
    g1b[(size_t)b * HWq + qy * Wq + qx] = (q00 + q01 + q10 + q11) * 0.25f;
}

// Fused pyramid levels 2+3 for both images: one thread per level-3 pixel,
// reads 4x4 of level-1 via float4, writes 2x2 of level-2 + 1 level-3 pixel.
__global__ void down2_kernel(const float* __restrict__ l1a, const float* __restrict__ l1b,
                             float* __restrict__ l2a, float* __restrict__ l2b,
                             float* __restrict__ l3a, float* __restrict__ l3b) {
    const int W3 = 64, W2 = 128, W1 = 256;
    int i = blockIdx.x * blockDim.x + threadIdx.x;
    int total = 2 * NB * W3 * W3;
    if (i >= total) return;
    int x3 = i % W3;
    int y3 = (i / W3) % W3;
    int b = (i / (W3 * W3)) % NB;
    int j = i / (NB * W3 * W3);
    const float* l1 = (j ? l1b : l1a) + (size_t)b * W1 * W1;
    float* l2 = (j ? l2b : l2a) + (size_t)b * W2 * W2;
    float* l3 = (j ? l3b : l3a) + (size_t)b * W3 * W3;
    float4 r0 = *(const float4*)(l1 + (size_t)(4 * y3 + 0) * W1 + 4 * x3);
    float4 r1 = *(const float4*)(l1 + (size_t)(4 * y3 + 1) * W1 + 4 * x3);
    float4 r2 = *(const float4*)(l1 + (size_t)(4 * y3 + 2) * W1 + 4 * x3);
    float4 r3 = *(const float4*)(l1 + (size_t)(4 * y3 + 3) * W1 + 4 * x3);
    float a00 = (r0.x + r0.y + r1.x + r1.y) * 0.25f;
    float a01 = (r0.z + r0.w + r1.z + r1.w) * 0.25f;
    float a10 = (r2.x + r2.y + r3.x + r3.y) * 0.25f;
    float a11 = (r2.z + r2.w + r3.z + r3.w) * 0.25f;
    *(f2*)(l2 + (size_t)(2 * y3) * W2 + 2 * x3) = (f2){a00, a01};
    *(f2*)(l2 + (size_t)(2 * y3 + 1) * W2 + 2 * x3) = (f2){a10, a11};
    l3[y3 * W3 + x3] = (a00 + a01 + a10 + a11) * 0.25f;
}

// Fused per-level LK: inline flow upsample (MODE=1) or zero flow (MODE=0),
// branch-free warp + Sobel + It + products, separable 5x5 box, 2x2 solve.
template <int MODE>
__global__ __launch_bounds__(256) void lk_kernel(
    const float* __restrict__ g1, const float* __restrict__ g2,
    const float* __restrict__ fin, float* __restrict__ fout, int H, int W) {
    __shared__ float sG[GR][SW];
    __shared__ float sU[PR][SW], sV[PR][SW];
    __shared__ float sP[5][PR][SW];
    __shared__ float sH[5][PR][16];

    int nbx = W / TS;
    int b = blockIdx.x % NB;
    int t = blockIdx.x / NB;
    int ty0 = (t / nbx) * TS, tx0 = (t % nbx) * TS;
    int tid = threadIdx.x;
    int lx = tid % TS, ly = tid / TS;

    const float* G1 = g1 + (size_t)b * H * W;
    const float* G2 = g2 + (size_t)b * H * W;
    // block-uniform: whole halo region in-bounds?
    bool interior = (ty0 >= 3) && (ty0 + TS + 3 <= H) && (tx0 >= 3) && (tx0 + TS + 3 <= W);

    // phase 0: stage G1 tile with halo 3 (zero-padded)
    if (interior) {
        for (int i = tid; i < GR * GR; i += 256) {
            int r = i / GR, c = i % GR;
            sG[r][c] = G1[(ty0 - 3 + r) * W + (tx0 - 3 + c)];
        }
    } else {
        for (int i = tid; i < GR * GR; i += 256) {
            int r = i / GR, c = i % GR;
            int gy = ty0 - 3 + r, gx = tx0 - 3 + c;
            float v = 0.0f;
            if (gy >= 0 && gy < H && gx >= 0 && gx < W) v = G1[gy * W + gx];
            sG[r][c] = v;
        }
    }
    // phase 1: flow for the 20x20 region (inline align-corners 2x upsample *2).
    // Halo flow values outside the image are extrapolated; harmless since those
    // pixels' products are zeroed in phase 2 (matches reference zero-padding).
    if (MODE == 1) {
        int Hs = H >> 1, Ws = W >> 1;
        float scale = (float)(Hs - 1) / (float)(H - 1);
        const float* FU = fin + (size_t)b * 2 * Hs * Ws;
        const float* FV = FU + Hs * Ws;
        for (int i = tid; i < PR * PR; i += 256) {
            int r = i / PR, c = i % PR;
            int gy = ty0 - 2 + r, gx = tx0 - 2 + c;
            float sy = (float)gy * scale;
            float sx = (float)gx * scale;
            int y0 = min(max((int)sy, 0), Hs - 2);
            int x0 = min(max((int)sx, 0), Ws - 2);
            float wy = sy - (float)y0, wx = sx - (float)x0;
            const float* pu = FU + (size_t)y0 * Ws + x0;
            const float* pv = FV + (size_t)y0 * Ws + x0;
            float ut = pu[0] * (1.0f - wy) + pu[Ws] * wy;
            float ub = pu[1] * (1.0f - wy) + pu[Ws + 1] * wy;
            float vt = pv[0] * (1.0f - wy) + pv[Ws] * wy;
            float vb = pv[1] * (1.0f - wy) + pv[Ws + 1] * wy;
            sU[r][c] = 2.0f * (ut * (1.0f - wx) + ub * wx);
            sV[r][c] = 2.0f * (vt * (1.0f - wx) + vb * wx);
        }
    } else {
        for (int i = tid; i < PR * PR; i += 256) {
            int r = i / PR, c = i % PR;
            sU[r][c] = 0.0f;
            sV[r][c] = 0.0f;
        }
    }
    __syncthreads();

    // phase 2: Sobel + branch-free warp + It + 5 products for the 20x20 region
#pragma unroll
    for (int it = 0; it < 2; ++it) {
        int i = tid + it * 256;
        if (i < PR * PR) {
            int r = i / PR, c = i % PR;
            int gy = ty0 - 2 + r, gx = tx0 - 2 + c;
            float su = sU[r][c], sv = sV[r][c];
            float xx = (float)gx + su, yy = (float)gy + sv;
            float x0f = floorf(xx), y0f = floorf(yy);
            float wx = xx - x0f, wy = yy - y0f;
            int xi = (int)x0f, yi = (int)y0f;
            int xc0 = min(max(xi, 0), W - 1), xc1 = min(max(xi + 1, 0), W - 1);
            int yc0 = min(max(yi, 0), H - 1), yc1 = min(max(yi + 1, 0), H - 1);
            // unconditional clamped loads (issue early)
            float v00 = G2[yc0 * W + xc0];
            float v01 = G2[yc0 * W + xc1];
            float v10 = G2[yc1 * W + xc0];
            float v11 = G2[yc1 * W + xc1];
            // validity folded into weights
            float Wm1 = (float)(W - 1), Hm1 = (float)(H - 1);
            float mx0 = (x0f >= 0.0f && x0f <= Wm1) ? 1.0f : 0.0f;
            float mx1 = (x0f + 1.0f >= 0.0f && x0f + 1.0f <= Wm1) ? 1.0f : 0.0f;
            float my0 = (y0f >= 0.0f && y0f <= Hm1) ? 1.0f : 0.0f;
            float my1 = (y0f + 1.0f >= 0.0f && y0f + 1.0f <= Hm1) ? 1.0f : 0.0f;
            float Ix = (-sG[r][c] + sG[r][c + 2]
                        - 2.0f * sG[r + 1][c] + 2.0f * sG[r + 1][c + 2]
                        - sG[r + 2][c] + sG[r + 2][c + 2]) * 0.125f;
            float Iy = (-sG[r][c] - 2.0f * sG[r][c + 1] - sG[r][c + 2]
                        + sG[r + 2][c] + 2.0f * sG[r + 2][c + 1] + sG[r + 2][c + 2]) * 0.125f;
            float I2w = v00 * ((1.0f - wx) * (1.0f - wy) * mx0 * my0)
                      + v01 * (wx * (1.0f - wy) * mx1 * my0)
                      + v10 * ((1.0f - wx) * wy * mx0 * my1)
                      + v11 * (wx * wy * mx1 * my1);
            float It = I2w - sG[r + 1][c + 1];
            // zero products for out-of-image pixels (reference zero-padding)
            float vm = (interior || (gy >= 0 && gy < H && gx >= 0 && gx < W)) ? 1.0f : 0.0f;
            Ix *= vm; Iy *= vm; It *= vm;
            sP[0][r][c] = Ix * Ix;
            sP[1][r][c] = Iy * Iy;
            sP[2][r][c] = Ix * Iy;
            sP[3][r][c] = Ix * It;
            sP[4][r][c] = Iy * It;
        }
    }
    __syncthreads();

    // phase 3: horizontal 5-sums -> sH[ch][r][x], r in [0,20), x in [0,16)
    for (int i = tid; i < 5 * PR * 16; i += 256) {
        int x = i % 16;
        int tt = i / 16;
        int r = tt % PR;
        int ch = tt / PR;
        const float* row = &sP[ch][r][x];
        sH[ch][r][x] = row[0] + row[1] + row[2] + row[3] + row[4];
    }
    __syncthreads();

    // phase 4: vertical 5-sums + 2x2 solve + flow update
    float Sxx = 0.f, Syy = 0.f, Sxy = 0.f, Sxt = 0.f, Syt = 0.f;
#pragma unroll
    for (int dy = 0; dy < 5; ++dy) {
        Sxx += sH[0][ly + dy][lx];
        Syy += sH[1][ly + dy][lx];
        Sxy += sH[2][ly + dy][lx];
        Sxt += sH[3][ly + dy][lx];
        Syt += sH[4][ly + dy][lx];
    }
    float inv = 1.0f / (Sxx * Syy - Sxy * Sxy + 1e-6f);
    float du = (-Syy * Sxt + Sxy * Syt) * inv;
    float dv = (Sxy * Sxt - Sxx * Syt) * inv;
    int gy = ty0 + ly, gx = tx0 + lx;
    float* FOU = fout + (size_t)b * 2 * H * W;
    FOU[gy * W + gx] = sU[ly + 2][lx + 2] + du;
    FOU[H * W + gy * W + gx] = sV[ly + 2][lx + 2] + dv;
}

extern "C" void kernel_launch(void* const* d_in, const int* in_sizes, int n_in,
                              void* d_out, int out_size, void* d_ws, size_t ws_size,
                              hipStream_t stream) {
    const float* img1 = (const float*)d_in[0];
    const float* img2 = (const float*)d_in[1];
    float* out = (float*)d_out;
    float* ws = (float*)d_ws;

    const int Hl[4] = {512, 256, 128, 64};
    size_t goff[4];
    size_t tot = 0;
    for (int l = 0; l < 4; ++l) {
        goff[l] = tot;
        tot += (size_t)NB * Hl[l] * Hl[l];
    }
    float* p1 = ws;            // gray pyramid img1
    float* p2 = ws + tot;      // gray pyramid img2
    float* f64 = p2 + tot;
    float* f128 = f64 + (size_t)NB * 2 * 64 * 64;
    float* f256 = f128 + (size_t)NB * 2 * 128 * 128;

    // gray @512 + pool to @256 (both images), fused
    {
        int n = NB * 256 * 256;
        gray_pool_kernel<<<(n + 255) / 256, 256, 0, stream>>>(
            img1, img2, p1 + goff[0], p2 + goff[0], p1 + goff[1], p2 + goff[1]);
    }
    // pyramid levels 2+3 for both images, one launch
    {
        int n = 2 * NB * 64 * 64;
        down2_kernel<<<(n + 255) / 256, 256, 0, stream>>>(
            p1 + goff[1], p2 + goff[1], p1 + goff[2], p2 + goff[2], p1 + goff[3], p2 + goff[3]);
    }
    // coarse-to-fine LK
    {
        int nb = NB * (64 / TS) * (64 / TS);
        lk_kernel<0><<<nb, 256, 0, stream>>>(p1 + goff[3], p2 + goff[3], nullptr, f64, 64, 64);
    }
    {
        int nb = NB * (128 / TS) * (128 / TS);
        lk_kernel<1><<<nb, 256, 0, stream>>>(p1 + goff[2], p2 + goff[2], f64, f128, 128, 128);
    }
    {
        int nb = NB * (256 / TS) * (256 / TS);
        lk_kernel<1><<<nb, 256, 0, stream>>>(p1 + goff[1], p2 + goff[1], f128, f256, 256, 256);
    }
    {
        int nb = NB * (512 / TS) * (512 / TS);
        lk_kernel<1><<<nb, 256, 0, stream>>>(p1 + goff[0], p2 + goff[0], f256, out, 512, 512);
    }
}